// Round 12
// baseline (287.085 us; speedup 1.0000x reference)
//
#include <hip/hip_runtime.h>
#include <hip/hip_bf16.h>
#include <hip/hip_cooperative_groups.h>

namespace cg = cooperative_groups;

typedef __bf16 bf16;
typedef __attribute__((ext_vector_type(8))) __bf16 bf16x8;
typedef __attribute__((ext_vector_type(4))) __bf16 bf16x4;
typedef __attribute__((ext_vector_type(16))) float f32x16;

#define N_ROWS 16384
#define DIM 256
#define NJC 512           /* 32-col tiles */
#define NBLKS 768         /* preferred: 3 blocks/CU x 256 CU */
#define TPB 43            /* 33024 / 768 exactly (fallback loss kernel) */
#define NTILES 33024      /* sum_{it=0}^{127} (512-4it) */
#define NCU 256
#define SQK1 4.53981608f  /* sqrt(1/(0.07*ln2)): A pre-scaled so e^{z} = 2^{dot'} */
#define LN2F 0.69314718056f

#define WS_T_OFF (N_ROWS * DIM * 2)
#define WS_D_OFF (WS_T_OFF + N_ROWS * 4)

#define GLOAD_LDS(g, l)                                        \
    __builtin_amdgcn_global_load_lds(                          \
        (const __attribute__((address_space(1))) void*)(g),    \
        (__attribute__((address_space(3))) void*)(l), 16, 0, 0)

// Tree-reduce 16 floats across the 32 `lo` lanes; every lane ends with the
// full sum for register index r = (lo>>1)&15. (Correctness-proven R4-R10.)
#define TREE16(R, out)                                                     \
    do {                                                                   \
        float w8[8], w4[4], w2[2], w1, g_;                                 \
        _Pragma("unroll") for (int i_ = 0; i_ < 8; ++i_) {                 \
            g_ = (lo & 16) ? R[i_] : R[i_ + 8];                            \
            w8[i_] = ((lo & 16) ? R[i_ + 8] : R[i_]) + __shfl_xor(g_, 16); \
        }                                                                  \
        _Pragma("unroll") for (int i_ = 0; i_ < 4; ++i_) {                 \
            g_ = (lo & 8) ? w8[i_] : w8[i_ + 4];                           \
            w4[i_] = ((lo & 8) ? w8[i_ + 4] : w8[i_]) + __shfl_xor(g_, 8); \
        }                                                                  \
        _Pragma("unroll") for (int i_ = 0; i_ < 2; ++i_) {                 \
            g_ = (lo & 4) ? w4[i_] : w4[i_ + 2];                           \
            w2[i_] = ((lo & 4) ? w4[i_ + 2] : w4[i_]) + __shfl_xor(g_, 4); \
        }                                                                  \
        g_ = (lo & 2) ? w2[0] : w2[1];                                     \
        w1 = ((lo & 2) ? w2[1] : w2[0]) + __shfl_xor(g_, 2);               \
        out = w1 + __shfl_xor(w1, 1);                                      \
    } while (0)

// ======================= fallback path (R17 verbatim) =======================

__global__ void __launch_bounds__(256) normalize_kernel(const float* __restrict__ in,
                                                        bf16* __restrict__ out,
                                                        float* __restrict__ Tg,
                                                        float* __restrict__ Dg,
                                                        float* __restrict__ loss_out) {
    if (blockIdx.x == 0 && threadIdx.x == 0) loss_out[0] = 0.0f;
    if (blockIdx.x < 64) Tg[blockIdx.x * 256 + threadIdx.x] = 0.0f;

    const int row  = blockIdx.x * 4 + (threadIdx.x >> 6);
    const int lane = threadIdx.x & 63;
    const float4* rp = (const float4*)(in + (size_t)row * DIM);
    float4 v = rp[lane];
    float ss = v.x * v.x + v.y * v.y + v.z * v.z + v.w * v.w;
#pragma unroll
    for (int m = 1; m < 64; m <<= 1) ss += __shfl_xor(ss, m, 64);
    float inv = SQK1 / fmaxf(sqrtf(ss), 1e-12f);
    bf16x4 o;
    o[0] = (bf16)(v.x * inv);
    o[1] = (bf16)(v.y * inv);
    o[2] = (bf16)(v.z * inv);
    o[3] = (bf16)(v.w * inv);
    *(bf16x4*)(out + (size_t)row * DIM + lane * 4) = o;

    float f0 = (float)o[0], f1 = (float)o[1], f2 = (float)o[2], f3 = (float)o[3];
    float s2 = f0 * f0 + f1 * f1 + f2 * f2 + f3 * f3;
#pragma unroll
    for (int m = 1; m < 64; m <<= 1) s2 += __shfl_xor(s2, m, 64);
    if (lane == 0) Dg[row] = s2;
}

__global__ void __launch_bounds__(256, 3)
loss_kernel(const bf16* __restrict__ A, float* __restrict__ Tg) {
    __shared__ bf16 Bs0[32 * DIM];
    __shared__ bf16 Bs1[32 * DIM];

    const int tid = threadIdx.x;
    const int w  = tid >> 6;
    const int l  = tid & 63;
    const int lo = l & 31, hi = l >> 5;

    const int tbeg = blockIdx.x * TPB;
    const int nrem = TPB;

    int it = 0;
    while (2 * (it + 1) * (257 - (it + 1)) <= tbeg) ++it;
    int jc = 4 * it + (tbeg - 2 * it * (257 - it));

    bf16x8 af[16];
#define LOAD_AF                                                              \
    do {                                                                     \
        const bf16* ap_ = A + (size_t)(it * 128 + w * 32 + lo) * DIM + hi * 8; \
        _Pragma("unroll") for (int k_ = 0; k_ < 16; ++k_)                    \
            af[k_] = *(const bf16x8*)(ap_ + k_ * 16);                        \
    } while (0)
    LOAD_AF;

    float s0[16];
#pragma unroll
    for (int r = 0; r < 16; ++r) s0[r] = 0.f;

    const int s_dma = l & 31;
    const int rl    = l >> 5;
    int vo[4];
#pragma unroll
    for (int q = 0; q < 4; ++q) {
        const int c = (s_dma & 24) | ((s_dma & 7) ^ ((q * 2 + rl) & 7));
        vo[q] = rl * DIM + c * 8;
    }

    const int rbase = lo * DIM;
    const int mx7 = lo & 7;

#define ISSUE(jcn_, BUF)                                                     \
    do {                                                                     \
        const bf16* tb_ = A + (size_t)((jcn_) * 32 + w * 8) * DIM;           \
        bf16* lb_ = &BUF[(w * 8) * DIM];                                     \
        _Pragma("unroll") for (int q_ = 0; q_ < 4; ++q_) {                   \
            GLOAD_LDS(tb_ + (q_ * 2) * DIM + vo[q_],                         \
                      lb_ + (q_ * 2) * DIM);                                 \
        }                                                                    \
    } while (0)

#define FLUSH_ROWS                                                           \
    do {                                                                     \
        float tr_;                                                           \
        TREE16(s0, tr_);                                                     \
        const int r_ = (lo >> 1) & 15;                                       \
        const int rowoff_ = (r_ & 3) + 8 * (r_ >> 2) + 4 * hi;               \
        if ((l & 1) == 0)                                                    \
            atomicAdd(&Tg[it * 128 + w * 32 + rowoff_], tr_);                \
    } while (0)

    int t = 0, jcn, itn;
    bool has_next;

#define NEXT_DECODE                                                          \
    do {                                                                     \
        has_next = (t + 1 < nrem);                                           \
        if (has_next) {                                                      \
            jcn = jc + 1; itn = it;                                          \
            if (jcn == NJC) { itn = it + 1; jcn = 4 * itn; }                 \
        } else { jcn = jc; itn = it; }                                       \
    } while (0)

#define TILE_BODY(BR, BW, WN, WL)                                            \
    do {                                                                     \
        asm volatile("s_barrier" ::: "memory");                              \
        if (has_next) {                                                      \
            ISSUE(jcn, BW);                                                  \
            asm volatile("s_waitcnt vmcnt(" #WN ")" ::: "memory");           \
        } else {                                                             \
            asm volatile("s_waitcnt vmcnt(" #WL ")" ::: "memory");           \
        }                                                                    \
        asm volatile("s_barrier" ::: "memory");                              \
        f32x16 c0;                                                           \
        _Pragma("unroll") for (int r_ = 0; r_ < 16; ++r_) c0[r_] = 0.f;      \
        __builtin_amdgcn_s_setprio(1);                                       \
        _Pragma("unroll") for (int k_ = 0; k_ < 16; ++k_) {                  \
            const int cc_ = k_ * 2 + hi;                                     \
            const int slot_ = (cc_ & 24) | ((cc_ & 7) ^ mx7);                \
            bf16x8 b_ = *(const bf16x8*)&BR[rbase + slot_ * 8];              \
            c0 = __builtin_amdgcn_mfma_f32_32x32x16_bf16(af[k_], b_, c0, 0, 0, 0); \
        }                                                                    \
        __builtin_amdgcn_s_setprio(0);                                       \
        float cs_ = 0.f;                                                     \
        _Pragma("unroll") for (int r_ = 0; r_ < 16; ++r_) {                  \
            float e_ = __builtin_amdgcn_exp2f(c0[r_]);                       \
            s0[r_] += e_;                                                    \
            cs_ += e_;                                                       \
        }                                                                    \
        cs_ += __shfl_xor(cs_, 32);                                          \
        const float fv_ = ((jc >> 2) == it) ? 0.0f : cs_;                    \
        if (hi == 0) atomicAdd(&Tg[jc * 32 + lo], fv_);                      \
    } while (0)

#define ADVANCE                                                              \
    do {                                                                     \
        ++t;                                                                 \
        if (itn != it) {                                                     \
            FLUSH_ROWS;                                                      \
            it = itn;                                                        \
            LOAD_AF;                                                         \
            _Pragma("unroll") for (int r_ = 0; r_ < 16; ++r_) s0[r_] = 0.f;  \
        }                                                                    \
        jc = jcn;                                                            \
    } while (0)

    ISSUE(jc, Bs0);
    NEXT_DECODE;
    TILE_BODY(Bs0, Bs1, 4, 0);
    ADVANCE;
    while (t < nrem) {
        NEXT_DECODE;
        TILE_BODY(Bs1, Bs0, 5, 1);
        ADVANCE;
        if (t >= nrem) break;
        NEXT_DECODE;
        TILE_BODY(Bs0, Bs1, 5, 1);
        ADVANCE;
    }
    FLUSH_ROWS;

#undef ISSUE
#undef TILE_BODY
#undef NEXT_DECODE
#undef ADVANCE
#undef FLUSH_ROWS
#undef LOAD_AF
}

__global__ void __launch_bounds__(256) final_kernel(const float* __restrict__ Tg,
                                                    const float* __restrict__ Dg,
                                                    float* __restrict__ out) {
    __shared__ float red[4];
    const int i = blockIdx.x * 256 + threadIdx.x;
    float c = LN2F * (__log2f(Tg[i]) - Dg[i]) * (1.0f / (float)N_ROWS);
#pragma unroll
    for (int m = 1; m < 64; m <<= 1) c += __shfl_xor(c, m, 64);
    if ((threadIdx.x & 63) == 0) red[threadIdx.x >> 6] = c;
    __syncthreads();
    if (threadIdx.x == 0)
        atomicAdd(out, red[0] + red[1] + red[2] + red[3]);
}

// ====================== fused cooperative path (R22) =======================
// R21 -> R22: the identical absmax across R20/R21 (1.513672e-02 == the
// reference loss itself) means OUT WAS NEVER WRITTEN: the cooperative
// launch failed synchronously (most plausibly TOO_LARGE: runtime occupancy
// for the fused kernel < 3 blocks/CU) and no kernel ran both rounds. Fix:
// (a) nblks is now a RUNTIME kernel arg; host queries
//     hipOccupancyMaxActiveBlocksPerMultiprocessor and launches
//     min(768, maxPerCU*256) -> TOO_LARGE is impossible by construction;
// (b) if the coop launch still errors, host FALLS BACK to the three-kernel
//     R17 path above (bounded downside: R17's passing 145.8 us).
// Phase 2 is R17-verbatim with an nblks-generic flat partition
// (tbeg = bid*NTILES/nblks). Cross-phase edges keep R21's agent-scope
// atomics (Tg zeros, A, Dg stores; phase-3 loads).
__global__ void __launch_bounds__(256, 3)
fused_kernel(const float* __restrict__ in, bf16* __restrict__ A,
             float* __restrict__ Tg, float* __restrict__ Dg,
             float* __restrict__ out, int nblks) {
    __shared__ bf16 Bs0[32 * DIM];
    __shared__ bf16 Bs1[32 * DIM];
    __shared__ float red[4];

    cg::grid_group grid = cg::this_grid();

    const int tid = threadIdx.x;
    const int bid = (int)blockIdx.x;

    // ================= phase 1: normalize + zero Tg =================
    {
        if (bid < 64)
            __hip_atomic_store(&Tg[bid * 256 + tid], 0.0f,
                               __ATOMIC_RELAXED, __HIP_MEMORY_SCOPE_AGENT);
        const int lane = tid & 63;
        for (int rg = bid; rg < (N_ROWS / 4); rg += nblks) {
            const int row = rg * 4 + (tid >> 6);
            const float4* rp = (const float4*)(in + (size_t)row * DIM);
            float4 v = rp[lane];
            float ss = v.x * v.x + v.y * v.y + v.z * v.z + v.w * v.w;
#pragma unroll
            for (int m = 1; m < 64; m <<= 1) ss += __shfl_xor(ss, m, 64);
            float inv = SQK1 / fmaxf(sqrtf(ss), 1e-12f);
            bf16x4 o;
            o[0] = (bf16)(v.x * inv);
            o[1] = (bf16)(v.y * inv);
            o[2] = (bf16)(v.z * inv);
            o[3] = (bf16)(v.w * inv);
            union { bf16x4 v4; unsigned long long u64; } pun;
            pun.v4 = o;
            __hip_atomic_store(
                reinterpret_cast<unsigned long long*>(A + (size_t)row * DIM + lane * 4),
                pun.u64, __ATOMIC_RELAXED, __HIP_MEMORY_SCOPE_AGENT);

            float f0 = (float)o[0], f1 = (float)o[1];
            float f2 = (float)o[2], f3 = (float)o[3];
            float s2 = f0 * f0 + f1 * f1 + f2 * f2 + f3 * f3;
#pragma unroll
            for (int m = 1; m < 64; m <<= 1) s2 += __shfl_xor(s2, m, 64);
            if (lane == 0)
                __hip_atomic_store(&Dg[row], s2,
                                   __ATOMIC_RELAXED, __HIP_MEMORY_SCOPE_AGENT);
        }
    }

    grid.sync();

    // ================= phase 2: loss (R17, nblks-generic partition) ========
    {
        const int w  = tid >> 6;
        const int l  = tid & 63;
        const int lo = l & 31, hi = l >> 5;

        const int tbeg = (int)(((long long)bid * NTILES) / nblks);
        const int tend = (int)(((long long)(bid + 1) * NTILES) / nblks);
        const int nrem = tend - tbeg;

        int it = 0;
        while (2 * (it + 1) * (257 - (it + 1)) <= tbeg) ++it;
        int jc = 4 * it + (tbeg - 2 * it * (257 - it));

        bf16x8 af[16];
#define LOAD_AF                                                              \
    do {                                                                     \
        const bf16* ap_ = A + (size_t)(it * 128 + w * 32 + lo) * DIM + hi * 8; \
        _Pragma("unroll") for (int k_ = 0; k_ < 16; ++k_)                    \
            af[k_] = *(const bf16x8*)(ap_ + k_ * 16);                        \
    } while (0)
        LOAD_AF;

        float s0[16];
#pragma unroll
        for (int r = 0; r < 16; ++r) s0[r] = 0.f;

        const int s_dma = l & 31;
        const int rl    = l >> 5;
        int vo[4];
#pragma unroll
        for (int q = 0; q < 4; ++q) {
            const int c = (s_dma & 24) | ((s_dma & 7) ^ ((q * 2 + rl) & 7));
            vo[q] = rl * DIM + c * 8;
        }

        const int rbase = lo * DIM;
        const int mx7 = lo & 7;

#define ISSUE(jcn_, BUF)                                                     \
    do {                                                                     \
        const bf16* tb_ = A + (size_t)((jcn_) * 32 + w * 8) * DIM;           \
        bf16* lb_ = &BUF[(w * 8) * DIM];                                     \
        _Pragma("unroll") for (int q_ = 0; q_ < 4; ++q_) {                   \
            GLOAD_LDS(tb_ + (q_ * 2) * DIM + vo[q_],                         \
                      lb_ + (q_ * 2) * DIM);                                 \
        }                                                                    \
    } while (0)

#define FLUSH_ROWS                                                           \
    do {                                                                     \
        float tr_;                                                           \
        TREE16(s0, tr_);                                                     \
        const int r_ = (lo >> 1) & 15;                                       \
        const int rowoff_ = (r_ & 3) + 8 * (r_ >> 2) + 4 * hi;               \
        if ((l & 1) == 0)                                                    \
            atomicAdd(&Tg[it * 128 + w * 32 + rowoff_], tr_);                \
    } while (0)

        int t = 0, jcn, itn;
        bool has_next;

#define NEXT_DECODE                                                          \
    do {                                                                     \
        has_next = (t + 1 < nrem);                                           \
        if (has_next) {                                                      \
            jcn = jc + 1; itn = it;                                          \
            if (jcn == NJC) { itn = it + 1; jcn = 4 * itn; }                 \
        } else { jcn = jc; itn = it; }                                       \
    } while (0)

#define TILE_BODY(BR, BW, WN, WL)                                            \
    do {                                                                     \
        asm volatile("s_barrier" ::: "memory");                              \
        if (has_next) {                                                      \
            ISSUE(jcn, BW);                                                  \
            asm volatile("s_waitcnt vmcnt(" #WN ")" ::: "memory");           \
        } else {                                                             \
            asm volatile("s_waitcnt vmcnt(" #WL ")" ::: "memory");           \
        }                                                                    \
        asm volatile("s_barrier" ::: "memory");                              \
        f32x16 c0;                                                           \
        _Pragma("unroll") for (int r_ = 0; r_ < 16; ++r_) c0[r_] = 0.f;      \
        __builtin_amdgcn_s_setprio(1);                                       \
        _Pragma("unroll") for (int k_ = 0; k_ < 16; ++k_) {                  \
            const int cc_ = k_ * 2 + hi;                                     \
            const int slot_ = (cc_ & 24) | ((cc_ & 7) ^ mx7);                \
            bf16x8 b_ = *(const bf16x8*)&BR[rbase + slot_ * 8];              \
            c0 = __builtin_amdgcn_mfma_f32_32x32x16_bf16(af[k_], b_, c0, 0, 0, 0); \
        }                                                                    \
        __builtin_amdgcn_s_setprio(0);                                       \
        float cs_ = 0.f;                                                     \
        _Pragma("unroll") for (int r_ = 0; r_ < 16; ++r_) {                  \
            float e_ = __builtin_amdgcn_exp2f(c0[r_]);                       \
            s0[r_] += e_;                                                    \
            cs_ += e_;                                                       \
        }                                                                    \
        cs_ += __shfl_xor(cs_, 32);                                          \
        const float fv_ = ((jc >> 2) == it) ? 0.0f : cs_;                    \
        if (hi == 0) atomicAdd(&Tg[jc * 32 + lo], fv_);                      \
    } while (0)

#define ADVANCE                                                              \
    do {                                                                     \
        ++t;                                                                 \
        if (itn != it) {                                                     \
            FLUSH_ROWS;                                                      \
            it = itn;                                                        \
            LOAD_AF;                                                         \
            _Pragma("unroll") for (int r_ = 0; r_ < 16; ++r_) s0[r_] = 0.f;  \
        }                                                                    \
        jc = jcn;                                                            \
    } while (0)

        ISSUE(jc, Bs0);
        NEXT_DECODE;
        TILE_BODY(Bs0, Bs1, 4, 0);
        ADVANCE;
        while (t < nrem) {
            NEXT_DECODE;
            TILE_BODY(Bs1, Bs0, 5, 1);
            ADVANCE;
            if (t >= nrem) break;
            NEXT_DECODE;
            TILE_BODY(Bs0, Bs1, 5, 1);
            ADVANCE;
        }
        FLUSH_ROWS;

#undef ISSUE
#undef TILE_BODY
#undef NEXT_DECODE
#undef ADVANCE
#undef FLUSH_ROWS
#undef LOAD_AF
    }

    grid.sync();

    // ================= phase 3: final reduce (block 0 only) =================
    if (bid == 0) {
        float c = 0.f;
        for (int i = tid; i < N_ROWS; i += 256) {
            float tv = __hip_atomic_load(&Tg[i], __ATOMIC_RELAXED,
                                         __HIP_MEMORY_SCOPE_AGENT);
            float dv = __hip_atomic_load(&Dg[i], __ATOMIC_RELAXED,
                                         __HIP_MEMORY_SCOPE_AGENT);
            c += __log2f(tv) - dv;
        }
#pragma unroll
        for (int m = 1; m < 64; m <<= 1) c += __shfl_xor(c, m, 64);
        if ((tid & 63) == 0) red[tid >> 6] = c;
        __syncthreads();
        if (tid == 0)
            out[0] = LN2F * (red[0] + red[1] + red[2] + red[3])
                     * (1.0f / (float)N_ROWS);
    }
}

extern "C" void kernel_launch(void* const* d_in, const int* in_sizes, int n_in,
                              void* d_out, int out_size, void* d_ws, size_t ws_size,
                              hipStream_t stream) {
    const float* emb = (const float*)d_in[0];
    float* out = (float*)d_out;
    bf16* Abf = (bf16*)d_ws;
    float* Tg = (float*)((char*)d_ws + WS_T_OFF);
    float* Dg = (float*)((char*)d_ws + WS_D_OFF);

    // Size the cooperative grid to what actually fits (host-side query; no
    // stream ops -> graph-capture safe). Falls back to 3-kernel path on any
    // launch error.
    int maxPerCU = 0;
    hipError_t qe = hipOccupancyMaxActiveBlocksPerMultiprocessor(
        &maxPerCU, fused_kernel, 256, 0);
    int nblks = NBLKS;
    if (qe == hipSuccess && maxPerCU >= 1 && maxPerCU * NCU < nblks)
        nblks = maxPerCU * NCU;
    if (nblks < 64) nblks = 64;  // Tg-zero needs >= 64 blocks

    void* args[] = {(void*)&emb, (void*)&Abf, (void*)&Tg, (void*)&Dg,
                    (void*)&out, (void*)&nblks};
    hipError_t le = hipLaunchCooperativeKernel(fused_kernel, dim3(nblks),
                                               dim3(256), args, 0, stream);
    if (le != hipSuccess) {
        // Fallback: proven three-kernel R17 path.
        hipLaunchKernelGGL(normalize_kernel, dim3(N_ROWS / 4), dim3(256), 0,
                           stream, emb, Abf, Tg, Dg, out);
        hipLaunchKernelGGL(loss_kernel, dim3(NBLKS), dim3(256), 0, stream,
                           Abf, Tg);
        hipLaunchKernelGGL(final_kernel, dim3(N_ROWS / 256), dim3(256), 0,
                           stream, Tg, Dg, out);
    }
}

// Round 13
// 159.843 us; speedup vs baseline: 1.7960x; 1.7960x over previous
//
#include <hip/hip_runtime.h>
#include <hip/hip_bf16.h>

typedef __bf16 bf16;
typedef __attribute__((ext_vector_type(8))) __bf16 bf16x8;
typedef __attribute__((ext_vector_type(4))) __bf16 bf16x4;
typedef __attribute__((ext_vector_type(16))) float f32x16;

#define N_ROWS 16384
#define DIM 256
#define NJC 512           /* 32-col tiles */
#define NBLKS 768         /* 3 blocks/CU x 256 CU = exact residency */
#define TPB 43            /* 33024 / 768 exactly */
#define NTILES 33024      /* sum_{it=0}^{127} (512-4it) */
#define SQK1 4.53981608f  /* sqrt(1/(0.07*ln2)): A pre-scaled so e^{z} = 2^{dot'} */
#define LN2F 0.69314718056f

#define WS_T_OFF (N_ROWS * DIM * 2)
#define WS_D_OFF (WS_T_OFF + N_ROWS * 4)
#define WS_C_OFF (WS_D_OFF + N_ROWS * 4)

#define GLOAD_LDS(g, l)                                        \
    __builtin_amdgcn_global_load_lds(                          \
        (const __attribute__((address_space(1))) void*)(g),    \
        (__attribute__((address_space(3))) void*)(l), 16, 0, 0)

// Kernel 1: L2-normalize rows, scale by SQK1, emit bf16 A' to ws. Zeros T[],
// the completion counter, and d_out. Dg[row] = s2' = sum(bf16(SQK1*a)^2) =
// the MFMA diagonal, so the diagonal's bf16 rounding error cancels:
// loss_i = ln2*(log2(T'_i) - s2'_i).
__global__ void __launch_bounds__(256) normalize_kernel(const float* __restrict__ in,
                                                        bf16* __restrict__ out,
                                                        float* __restrict__ Tg,
                                                        float* __restrict__ Dg,
                                                        float* __restrict__ loss_out,
                                                        unsigned int* __restrict__ cnt) {
    if (blockIdx.x == 0 && threadIdx.x == 0) { loss_out[0] = 0.0f; *cnt = 0u; }
    if (blockIdx.x < 64) Tg[blockIdx.x * 256 + threadIdx.x] = 0.0f;

    const int row  = blockIdx.x * 4 + (threadIdx.x >> 6);
    const int lane = threadIdx.x & 63;
    const float4* rp = (const float4*)(in + (size_t)row * DIM);
    float4 v = rp[lane];
    float ss = v.x * v.x + v.y * v.y + v.z * v.z + v.w * v.w;
#pragma unroll
    for (int m = 1; m < 64; m <<= 1) ss += __shfl_xor(ss, m, 64);
    float inv = SQK1 / fmaxf(sqrtf(ss), 1e-12f);
    bf16x4 o;
    o[0] = (bf16)(v.x * inv);
    o[1] = (bf16)(v.y * inv);
    o[2] = (bf16)(v.z * inv);
    o[3] = (bf16)(v.w * inv);
    *(bf16x4*)(out + (size_t)row * DIM + lane * 4) = o;

    float f0 = (float)o[0], f1 = (float)o[1], f2 = (float)o[2], f3 = (float)o[3];
    float s2 = f0 * f0 + f1 * f1 + f2 * f2 + f3 * f3;
#pragma unroll
    for (int m = 1; m < 64; m <<= 1) s2 += __shfl_xor(s2, m, 64);
    if (lane == 0) Dg[row] = s2;
}

// Tree-reduce 16 floats across the 32 `lo` lanes; every lane ends with the
// full sum for register index r = (lo>>1)&15. (Correctness-proven R4-R10.)
#define TREE16(R, out)                                                     \
    do {                                                                   \
        float w8[8], w4[4], w2[2], w1, g_;                                 \
        _Pragma("unroll") for (int i_ = 0; i_ < 8; ++i_) {                 \
            g_ = (lo & 16) ? R[i_] : R[i_ + 8];                            \
            w8[i_] = ((lo & 16) ? R[i_ + 8] : R[i_]) + __shfl_xor(g_, 16); \
        }                                                                  \
        _Pragma("unroll") for (int i_ = 0; i_ < 4; ++i_) {                 \
            g_ = (lo & 8) ? w8[i_] : w8[i_ + 4];                           \
            w4[i_] = ((lo & 8) ? w8[i_ + 4] : w8[i_]) + __shfl_xor(g_, 8); \
        }                                                                  \
        _Pragma("unroll") for (int i_ = 0; i_ < 2; ++i_) {                 \
            g_ = (lo & 4) ? w4[i_] : w4[i_ + 2];                           \
            w2[i_] = ((lo & 4) ? w4[i_ + 2] : w4[i_]) + __shfl_xor(g_, 4); \
        }                                                                  \
        g_ = (lo & 2) ? w2[0] : w2[1];                                     \
        w1 = ((lo & 2) ? w2[1] : w2[0]) + __shfl_xor(g_, 2);               \
        out = w1 + __shfl_xor(w1, 1);                                      \
    } while (0)

// Kernel 2: symmetric A'A'^T + softmax denominator + LAST-BLOCK FINALIZE.
// R22 -> R23: the fused-coop arc is closed (it ran in R22: 276 us, 3x the
// 3-kernel sum, mechanism unexplained — not stacking more on it). R22's
// useful datum: single-kernel harness gap ~11 us vs ~50 us for 3 kernels
// -> each kernel boundary costs ~25 us. This round removes ONE boundary
// without any grid-wide barrier: loss_kernel absorbs final_kernel via a
// completion counter. Per block: after its row flush, __syncthreads()
// (barrier semantics drain every wave's outstanding atomics to the LLC),
// thread 0 does fetch_add(cnt, ACQ_REL, AGENT); the block seeing
// old==NBLKS-1 knows ALL blocks' Tg atomics have landed, re-reads Tg/Dg
// via agent-scope loads (bypass possibly-stale per-XCD L2) and writes
// out[0] (single writer). Phase-2 tile loop is byte-identical to R17's
// proven kernel (85.5 us; FETCH 97MB; conflicts 8.45M).
__global__ void __launch_bounds__(256, 3)
loss_kernel(const bf16* __restrict__ A, float* __restrict__ Tg,
            const float* __restrict__ Dg, float* __restrict__ out,
            unsigned int* __restrict__ cnt) {
    __shared__ bf16 Bs0[32 * DIM];          // 16 KB
    __shared__ bf16 Bs1[32 * DIM];          // 16 KB
    __shared__ float red[4];
    __shared__ int last_flag;

    const int tid = threadIdx.x;
    const int w  = tid >> 6;      // wave = row-group: rows w*32..+31 of the 128-row strip
    const int l  = tid & 63;
    const int lo = l & 31, hi = l >> 5;

    // flat tile range for this block: exactly TPB tiles
    const int tbeg = blockIdx.x * TPB;
    const int nrem = TPB;

    // decode starting (it, jc): C(it) = 2*it*(257-it) <= tbeg < C(it+1)
    int it = 0;
    while (2 * (it + 1) * (257 - (it + 1)) <= tbeg) ++it;
    int jc = 4 * it + (tbeg - 2 * it * (257 - it));

    // persistent A fragments for the wave's 32 rows (A-op: m=lo, k=hi*8+j)
    bf16x8 af[16];
#define LOAD_AF                                                              \
    do {                                                                     \
        const bf16* ap_ = A + (size_t)(it * 128 + w * 32 + lo) * DIM + hi * 8; \
        _Pragma("unroll") for (int k_ = 0; k_ < 16; ++k_)                    \
            af[k_] = *(const bf16x8*)(ap_ + k_ * 16);                        \
    } while (0)
    LOAD_AF;

    float s0[16];
#pragma unroll
    for (int r = 0; r < 16; ++r) s0[r] = 0.f;

    // DMA lane constants. Wave w stages B-tile rows w*8..+7 in 4 instrs
    // (2 rows each). Lane: rl = l>>5 (row in pair), s = l&31 (LDS slot).
    // Slot s of row r holds global chunk c = (s&24)|((s&7)^(r&7)).
    const int s_dma = l & 31;
    const int rl    = l >> 5;
    int vo[4];
#pragma unroll
    for (int q = 0; q < 4; ++q) {
        const int c = (s_dma & 24) | ((s_dma & 7) ^ ((q * 2 + rl) & 7));
        vo[q] = rl * DIM + c * 8;
    }

    // fragment-read constants: B row = lo; chunk cc at slot (cc&24)|((cc&7)^(lo&7))
    const int rbase = lo * DIM;
    const int mx7 = lo & 7;

#define ISSUE(jcn_, BUF)                                                     \
    do {                                                                     \
        const bf16* tb_ = A + (size_t)((jcn_) * 32 + w * 8) * DIM;           \
        bf16* lb_ = &BUF[(w * 8) * DIM];                                     \
        _Pragma("unroll") for (int q_ = 0; q_ < 4; ++q_) {                   \
            GLOAD_LDS(tb_ + (q_ * 2) * DIM + vo[q_],                         \
                      lb_ + (q_ * 2) * DIM);                                 \
        }                                                                    \
    } while (0)

#define FLUSH_ROWS                                                           \
    do {                                                                     \
        float tr_;                                                           \
        TREE16(s0, tr_);                                                     \
        const int r_ = (lo >> 1) & 15;                                       \
        const int rowoff_ = (r_ & 3) + 8 * (r_ >> 2) + 4 * hi;               \
        if ((l & 1) == 0)                                                    \
            atomicAdd(&Tg[it * 128 + w * 32 + rowoff_], tr_);                \
    } while (0)

    int t = 0, jcn, itn;
    bool has_next;

#define NEXT_DECODE                                                          \
    do {                                                                     \
        has_next = (t + 1 < nrem);                                           \
        if (has_next) {                                                      \
            jcn = jc + 1; itn = it;                                          \
            if (jcn == NJC) { itn = it + 1; jcn = 4 * itn; }                 \
        } else { jcn = jc; itn = it; }                                       \
    } while (0)

    // WN = steady wait (next issued), WL = last-tile wait (no next issued)
#define TILE_BODY(BR, BW, WN, WL)                                            \
    do {                                                                     \
        asm volatile("s_barrier" ::: "memory");                              \
        if (has_next) {                                                      \
            ISSUE(jcn, BW);                                                  \
            asm volatile("s_waitcnt vmcnt(" #WN ")" ::: "memory");           \
        } else {                                                             \
            asm volatile("s_waitcnt vmcnt(" #WL ")" ::: "memory");           \
        }                                                                    \
        asm volatile("s_barrier" ::: "memory");                              \
        f32x16 c0;                                                           \
        _Pragma("unroll") for (int r_ = 0; r_ < 16; ++r_) c0[r_] = 0.f;      \
        __builtin_amdgcn_s_setprio(1);                                       \
        _Pragma("unroll") for (int k_ = 0; k_ < 16; ++k_) {                  \
            const int cc_ = k_ * 2 + hi;                                     \
            const int slot_ = (cc_ & 24) | ((cc_ & 7) ^ mx7);                \
            bf16x8 b_ = *(const bf16x8*)&BR[rbase + slot_ * 8];              \
            c0 = __builtin_amdgcn_mfma_f32_32x32x16_bf16(af[k_], b_, c0, 0, 0, 0); \
        }                                                                    \
        __builtin_amdgcn_s_setprio(0);                                       \
        float cs_ = 0.f;                                                     \
        _Pragma("unroll") for (int r_ = 0; r_ < 16; ++r_) {                  \
            float e_ = __builtin_amdgcn_exp2f(c0[r_]);                       \
            s0[r_] += e_;                                                    \
            cs_ += e_;                                                       \
        }                                                                    \
        cs_ += __shfl_xor(cs_, 32);                                          \
        /* col-sum flush: UNCONDITIONAL instr (uniform vmcnt queue); adds  */ \
        /* 0.0 on the diagonal 128x128 block (covered by row sums).        */ \
        const float fv_ = ((jc >> 2) == it) ? 0.0f : cs_;                    \
        if (hi == 0) atomicAdd(&Tg[jc * 32 + lo], fv_);                      \
    } while (0)

    // advance to next tile; at it-segment boundary: flush row sums, reload af
#define ADVANCE                                                              \
    do {                                                                     \
        ++t;                                                                 \
        if (itn != it) {                                                     \
            FLUSH_ROWS;                                                      \
            it = itn;                                                        \
            LOAD_AF;                                                         \
            _Pragma("unroll") for (int r_ = 0; r_ < 16; ++r_) s0[r_] = 0.f;  \
        }                                                                    \
        jc = jcn;                                                            \
    } while (0)

    ISSUE(jc, Bs0);
    // peeled first tile: no atomic in the queue yet -> vmcnt(4)/(0)
    NEXT_DECODE;
    TILE_BODY(Bs0, Bs1, 4, 0);
    ADVANCE;
    while (t < nrem) {
        NEXT_DECODE;
        TILE_BODY(Bs1, Bs0, 5, 1);
        ADVANCE;
        if (t >= nrem) break;
        NEXT_DECODE;
        TILE_BODY(Bs0, Bs1, 5, 1);
        ADVANCE;
    }
    FLUSH_ROWS;

    // ---- last-block finalization (replaces final_kernel) ----
    // __syncthreads drains every wave's outstanding vmem ops (incl. the
    // atomicAdds above) before the counter bump.
    __syncthreads();
    if (tid == 0) {
        unsigned int old = __hip_atomic_fetch_add(cnt, 1u, __ATOMIC_ACQ_REL,
                                                  __HIP_MEMORY_SCOPE_AGENT);
        last_flag = (old == (unsigned int)(NBLKS - 1)) ? 1 : 0;
    }
    __syncthreads();
    if (last_flag) {
        float c = 0.f;
#pragma unroll 4
        for (int i = tid; i < N_ROWS; i += 256) {
            float tv = __hip_atomic_load(&Tg[i], __ATOMIC_RELAXED,
                                         __HIP_MEMORY_SCOPE_AGENT);
            float dv = __hip_atomic_load((float*)&Dg[i], __ATOMIC_RELAXED,
                                         __HIP_MEMORY_SCOPE_AGENT);
            c += __log2f(tv) - dv;
        }
#pragma unroll
        for (int m = 1; m < 64; m <<= 1) c += __shfl_xor(c, m, 64);
        if ((tid & 63) == 0) red[tid >> 6] = c;
        __syncthreads();
        if (tid == 0)
            out[0] = LN2F * (red[0] + red[1] + red[2] + red[3])
                     * (1.0f / (float)N_ROWS);
    }

#undef ISSUE
#undef TILE_BODY
#undef NEXT_DECODE
#undef ADVANCE
#undef FLUSH_ROWS
#undef LOAD_AF
}

extern "C" void kernel_launch(void* const* d_in, const int* in_sizes, int n_in,
                              void* d_out, int out_size, void* d_ws, size_t ws_size,
                              hipStream_t stream) {
    const float* emb = (const float*)d_in[0];
    float* out = (float*)d_out;
    bf16* Abf = (bf16*)d_ws;
    float* Tg = (float*)((char*)d_ws + WS_T_OFF);
    float* Dg = (float*)((char*)d_ws + WS_D_OFF);
    unsigned int* cnt = (unsigned int*)((char*)d_ws + WS_C_OFF);

    hipLaunchKernelGGL(normalize_kernel, dim3(N_ROWS / 4), dim3(256), 0, stream,
                       emb, Abf, Tg, Dg, out, cnt);
    hipLaunchKernelGGL(loss_kernel, dim3(NBLKS), dim3(256), 0, stream,
                       Abf, Tg, Dg, out, cnt);
}

// Round 15
// 148.710 us; speedup vs baseline: 1.9305x; 1.0749x over previous
//
#include <hip/hip_runtime.h>
#include <hip/hip_bf16.h>

typedef __bf16 bf16;
typedef __attribute__((ext_vector_type(8))) __bf16 bf16x8;
typedef __attribute__((ext_vector_type(4))) __bf16 bf16x4;
typedef __attribute__((ext_vector_type(16))) float f32x16;

#define N_ROWS 16384
#define DIM 256
#define NJC 512           /* 32-col tiles */
#define NBLKS 768         /* 3 blocks/CU x 256 CU = exact residency (regs cap
                             us at 3 waves/SIMD) */
#define TPB 43            /* 33024 / 768 exactly */
#define NTILES 33024      /* sum_{it=0}^{127} (512-4it) */
#define SQK1 4.53981608f  /* sqrt(1/(0.07*ln2)): A pre-scaled so e^{z} = 2^{dot'} */
#define LN2F 0.69314718056f

#define WS_T_OFF (N_ROWS * DIM * 2)
#define WS_D_OFF (WS_T_OFF + N_ROWS * 4)

#define GLOAD_LDS(g, l)                                        \
    __builtin_amdgcn_global_load_lds(                          \
        (const __attribute__((address_space(1))) void*)(g),    \
        (__attribute__((address_space(3))) void*)(l), 16, 0, 0)

// Kernel 1: L2-normalize rows, scale by SQK1, emit bf16 A' to ws. Zeros T[]
// and d_out. Dg[row] = s2' = sum(bf16(SQK1*a)^2) = the MFMA diagonal, so the
// diagonal's bf16 rounding error cancels: loss_i = ln2*(log2(T'_i) - s2'_i).
__global__ void __launch_bounds__(256) normalize_kernel(const float* __restrict__ in,
                                                        bf16* __restrict__ out,
                                                        float* __restrict__ Tg,
                                                        float* __restrict__ Dg,
                                                        float* __restrict__ loss_out) {
    if (blockIdx.x == 0 && threadIdx.x == 0) loss_out[0] = 0.0f;
    if (blockIdx.x < 64) Tg[blockIdx.x * 256 + threadIdx.x] = 0.0f;

    const int row  = blockIdx.x * 4 + (threadIdx.x >> 6);
    const int lane = threadIdx.x & 63;
    const float4* rp = (const float4*)(in + (size_t)row * DIM);
    float4 v = rp[lane];
    float ss = v.x * v.x + v.y * v.y + v.z * v.z + v.w * v.w;
#pragma unroll
    for (int m = 1; m < 64; m <<= 1) ss += __shfl_xor(ss, m, 64);
    float inv = SQK1 / fmaxf(sqrtf(ss), 1e-12f);
    bf16x4 o;
    o[0] = (bf16)(v.x * inv);
    o[1] = (bf16)(v.y * inv);
    o[2] = (bf16)(v.z * inv);
    o[3] = (bf16)(v.w * inv);
    *(bf16x4*)(out + (size_t)row * DIM + lane * 4) = o;

    float f0 = (float)o[0], f1 = (float)o[1], f2 = (float)o[2], f3 = (float)o[3];
    float s2 = f0 * f0 + f1 * f1 + f2 * f2 + f3 * f3;
#pragma unroll
    for (int m = 1; m < 64; m <<= 1) s2 += __shfl_xor(s2, m, 64);
    if (lane == 0) Dg[row] = s2;
}

// Tree-reduce 16 floats across the 32 `lo` lanes; every lane ends with the
// full sum for register index r = (lo>>1)&15. (Correctness-proven R4-R10.)
#define TREE16(R, out)                                                     \
    do {                                                                   \
        float w8[8], w4[4], w2[2], w1, g_;                                 \
        _Pragma("unroll") for (int i_ = 0; i_ < 8; ++i_) {                 \
            g_ = (lo & 16) ? R[i_] : R[i_ + 8];                            \
            w8[i_] = ((lo & 16) ? R[i_ + 8] : R[i_]) + __shfl_xor(g_, 16); \
        }                                                                  \
        _Pragma("unroll") for (int i_ = 0; i_ < 4; ++i_) {                 \
            g_ = (lo & 8) ? w8[i_] : w8[i_ + 4];                           \
            w4[i_] = ((lo & 8) ? w8[i_ + 4] : w8[i_]) + __shfl_xor(g_, 8); \
        }                                                                  \
        _Pragma("unroll") for (int i_ = 0; i_ < 2; ++i_) {                 \
            g_ = (lo & 4) ? w4[i_] : w4[i_ + 2];                           \
            w2[i_] = ((lo & 4) ? w4[i_ + 2] : w4[i_]) + __shfl_xor(g_, 4); \
        }                                                                  \
        g_ = (lo & 2) ? w2[0] : w2[1];                                     \
        w1 = ((lo & 2) ? w2[1] : w2[0]) + __shfl_xor(g_, 2);               \
        out = w1 + __shfl_xor(w1, 1);                                      \
    } while (0)

// Kernel 2: symmetric A'A'^T + softmax denominator.
// R25 = R17 VERBATIM resubmit (R24 bench was an infrastructure failure —
// "container failed twice" — no signal; same env failure mode as R2).
// Champion: loss 85.5 us, total 145.8, passed twice. All structural arcs
// measured-dead: dual-panel 8B/out data path (R14/R15/R19 allocator-
// infeasible), epilogue fusion (R16), sync/buffer restructure (R18),
// grid fusion (R22), boundary elimination (R23). Governor: LDS pipe ~73%
// busy at the 16B/out data path; 3 blocks/CU exact residency; flat 129/4
// tile schedule.
__global__ void __launch_bounds__(256, 3)
loss_kernel(const bf16* __restrict__ A, float* __restrict__ Tg) {
    __shared__ bf16 Bs0[32 * DIM];          // 16 KB
    __shared__ bf16 Bs1[32 * DIM];          // 16 KB

    const int tid = threadIdx.x;
    const int w  = tid >> 6;      // wave = row-group: rows w*32..+31 of the 128-row strip
    const int l  = tid & 63;
    const int lo = l & 31, hi = l >> 5;

    // flat tile range for this block: exactly TPB tiles
    const int tbeg = blockIdx.x * TPB;
    const int nrem = TPB;

    // decode starting (it, jc): C(it) = 2*it*(257-it) <= tbeg < C(it+1)
    int it = 0;
    while (2 * (it + 1) * (257 - (it + 1)) <= tbeg) ++it;
    int jc = 4 * it + (tbeg - 2 * it * (257 - it));

    // persistent A fragments for the wave's 32 rows (A-op: m=lo, k=hi*8+j)
    bf16x8 af[16];
#define LOAD_AF                                                              \
    do {                                                                     \
        const bf16* ap_ = A + (size_t)(it * 128 + w * 32 + lo) * DIM + hi * 8; \
        _Pragma("unroll") for (int k_ = 0; k_ < 16; ++k_)                    \
            af[k_] = *(const bf16x8*)(ap_ + k_ * 16);                        \
    } while (0)
    LOAD_AF;

    float s0[16];
#pragma unroll
    for (int r = 0; r < 16; ++r) s0[r] = 0.f;

    // DMA lane constants. Wave w stages B-tile rows w*8..+7 in 4 instrs
    // (2 rows each). Lane: rl = l>>5 (row in pair), s = l&31 (LDS slot).
    // Slot s of row r holds global chunk c = (s&24)|((s&7)^(r&7)).
    const int s_dma = l & 31;
    const int rl    = l >> 5;
    int vo[4];
#pragma unroll
    for (int q = 0; q < 4; ++q) {
        const int c = (s_dma & 24) | ((s_dma & 7) ^ ((q * 2 + rl) & 7));
        vo[q] = rl * DIM + c * 8;
    }

    // fragment-read constants: B row = lo; chunk cc at slot (cc&24)|((cc&7)^(lo&7))
    const int rbase = lo * DIM;
    const int mx7 = lo & 7;

#define ISSUE(jcn_, BUF)                                                     \
    do {                                                                     \
        const bf16* tb_ = A + (size_t)((jcn_) * 32 + w * 8) * DIM;           \
        bf16* lb_ = &BUF[(w * 8) * DIM];                                     \
        _Pragma("unroll") for (int q_ = 0; q_ < 4; ++q_) {                   \
            GLOAD_LDS(tb_ + (q_ * 2) * DIM + vo[q_],                         \
                      lb_ + (q_ * 2) * DIM);                                 \
        }                                                                    \
    } while (0)

#define FLUSH_ROWS                                                           \
    do {                                                                     \
        float tr_;                                                           \
        TREE16(s0, tr_);                                                     \
        const int r_ = (lo >> 1) & 15;                                       \
        const int rowoff_ = (r_ & 3) + 8 * (r_ >> 2) + 4 * hi;               \
        if ((l & 1) == 0)                                                    \
            atomicAdd(&Tg[it * 128 + w * 32 + rowoff_], tr_);                \
    } while (0)

    int t = 0, jcn, itn;
    bool has_next;

#define NEXT_DECODE                                                          \
    do {                                                                     \
        has_next = (t + 1 < nrem);                                           \
        if (has_next) {                                                      \
            jcn = jc + 1; itn = it;                                          \
            if (jcn == NJC) { itn = it + 1; jcn = 4 * itn; }                 \
        } else { jcn = jc; itn = it; }                                       \
    } while (0)

    // WN = steady wait (next issued), WL = last-tile wait (no next issued)
#define TILE_BODY(BR, BW, WN, WL)                                            \
    do {                                                                     \
        asm volatile("s_barrier" ::: "memory");                              \
        if (has_next) {                                                      \
            ISSUE(jcn, BW);                                                  \
            asm volatile("s_waitcnt vmcnt(" #WN ")" ::: "memory");           \
        } else {                                                             \
            asm volatile("s_waitcnt vmcnt(" #WL ")" ::: "memory");           \
        }                                                                    \
        asm volatile("s_barrier" ::: "memory");                              \
        f32x16 c0;                                                           \
        _Pragma("unroll") for (int r_ = 0; r_ < 16; ++r_) c0[r_] = 0.f;      \
        __builtin_amdgcn_s_setprio(1);                                       \
        _Pragma("unroll") for (int k_ = 0; k_ < 16; ++k_) {                  \
            const int cc_ = k_ * 2 + hi;                                     \
            const int slot_ = (cc_ & 24) | ((cc_ & 7) ^ mx7);                \
            bf16x8 b_ = *(const bf16x8*)&BR[rbase + slot_ * 8];              \
            c0 = __builtin_amdgcn_mfma_f32_32x32x16_bf16(af[k_], b_, c0, 0, 0, 0); \
        }                                                                    \
        __builtin_amdgcn_s_setprio(0);                                       \
        float cs_ = 0.f;                                                     \
        _Pragma("unroll") for (int r_ = 0; r_ < 16; ++r_) {                  \
            float e_ = __builtin_amdgcn_exp2f(c0[r_]);                       \
            s0[r_] += e_;                                                    \
            cs_ += e_;                                                       \
        }                                                                    \
        cs_ += __shfl_xor(cs_, 32);                                          \
        /* col-sum flush: UNCONDITIONAL instr (uniform vmcnt queue); adds  */ \
        /* 0.0 on the diagonal 128x128 block (covered by row sums).        */ \
        const float fv_ = ((jc >> 2) == it) ? 0.0f : cs_;                    \
        if (hi == 0) atomicAdd(&Tg[jc * 32 + lo], fv_);                      \
    } while (0)

    // advance to next tile; at it-segment boundary: flush row sums, reload af
#define ADVANCE                                                              \
    do {                                                                     \
        ++t;                                                                 \
        if (itn != it) {                                                     \
            FLUSH_ROWS;                                                      \
            it = itn;                                                        \
            LOAD_AF;                                                         \
            _Pragma("unroll") for (int r_ = 0; r_ < 16; ++r_) s0[r_] = 0.f;  \
        }                                                                    \
        jc = jcn;                                                            \
    } while (0)

    ISSUE(jc, Bs0);
    // peeled first tile: no atomic in the queue yet -> vmcnt(4)/(0)
    NEXT_DECODE;
    TILE_BODY(Bs0, Bs1, 4, 0);
    ADVANCE;
    while (t < nrem) {
        NEXT_DECODE;
        TILE_BODY(Bs1, Bs0, 5, 1);
        ADVANCE;
        if (t >= nrem) break;
        NEXT_DECODE;
        TILE_BODY(Bs0, Bs1, 5, 1);
        ADVANCE;
    }
    FLUSH_ROWS;

#undef ISSUE
#undef TILE_BODY
#undef NEXT_DECODE
#undef ADVANCE
#undef FLUSH_ROWS
#undef LOAD_AF
}

// Kernel 3: loss_i = ln2*(log2(T'_i) - s2'_i), mean over rows.
__global__ void __launch_bounds__(256) final_kernel(const float* __restrict__ Tg,
                                                    const float* __restrict__ Dg,
                                                    float* __restrict__ out) {
    __shared__ float red[4];
    const int i = blockIdx.x * 256 + threadIdx.x;
    float c = LN2F * (__log2f(Tg[i]) - Dg[i]) * (1.0f / (float)N_ROWS);
#pragma unroll
    for (int m = 1; m < 64; m <<= 1) c += __shfl_xor(c, m, 64);
    if ((threadIdx.x & 63) == 0) red[threadIdx.x >> 6] = c;
    __syncthreads();
    if (threadIdx.x == 0)
        atomicAdd(out, red[0] + red[1] + red[2] + red[3]);
}

extern "C" void kernel_launch(void* const* d_in, const int* in_sizes, int n_in,
                              void* d_out, int out_size, void* d_ws, size_t ws_size,
                              hipStream_t stream) {
    const float* emb = (const float*)d_in[0];
    float* out = (float*)d_out;
    bf16* Abf = (bf16*)d_ws;
    float* Tg = (float*)((char*)d_ws + WS_T_OFF);
    float* Dg = (float*)((char*)d_ws + WS_D_OFF);

    hipLaunchKernelGGL(normalize_kernel, dim3(N_ROWS / 4), dim3(256), 0, stream,
                       emb, Abf, Tg, Dg, out);
    hipLaunchKernelGGL(loss_kernel, dim3(NBLKS), dim3(256), 0, stream,
                       Abf, Tg);
    hipLaunchKernelGGL(final_kernel, dim3(N_ROWS / 256), dim3(256), 0, stream,
                       Tg, Dg, out);
}